// Round 8
// baseline (2359.096 us; speedup 1.0000x reference)
//
#include <hip/hip_runtime.h>
#include <hip/hip_bf16.h>

// SRNN: x_{t+1} = x + DT*(-x + J@rates + inp), rates = 0.5*(1+tanh(x)),
// out[p,t] = (w_out @ rates_t)[p] / N.  J 5% dense -> paired bf16 ELL.
//
// v8 = v7 + k-pair contraction via v_dot2_f32_bf16:
//  - J quantized bf16 (analysis: fixed-bias ~1.6e-4/step on J@r -> readout
//    averaging over ~102 rows -> delta_out ~4e-7 << 1 output ulp 2^-13).
//  - ELL stored as PAIRS {u32 (j1:j0) bf16x2, u32 (idx1:idx0)} = 4B/nnz,
//    rows padded to mult-of-8 nnz with exact-zero pairs; waves own blocked
//    quarters -> clean unrolled loop, no remainder.
//  - inner 2-nnz iter: ds_read_b64 + 2 gathers (uint2) + v_perm repack of
//    rates into k-pairs + 4 v_dot2_f32_bf16 (~7 issues/nnz vs 12 in v7).
// [history: v2 2353; v4 coop grid.sync 25ms; v5 8w/CU 2824; v6 LDS tiles
//  4436; v7 bf16-rates 2114 (~10.1us/step: gather 3.2 + VALU 2.1 + launch
//  ~2 + phases ~1.5 overlap).]

#define NN 2048
#define PP 256
#define PAD 256          // raw ELL capacity per row (mean ~102, std ~10)
#define NPAIR 128        // paired capacity per row
#define DT_C 0.1f
#define ON_TIME_C 10

// ---- Build raw ELL {f32 val, idx} from dense J. One wave per row, ordered
// ballot compaction -> deterministic ascending-k order. ----
__global__ void build_ell_kernel(const float* __restrict__ J,
                                 float2* __restrict__ raw,
                                 int* __restrict__ nnz) {
    int row  = blockIdx.x * (blockDim.x >> 6) + (threadIdx.x >> 6);
    int lane = threadIdx.x & 63;
    if (row >= NN) return;
    const float* Jrow = J + (size_t)row * NN;
    int base = 0;
    for (int c = 0; c < NN / 64; ++c) {
        float f = Jrow[c * 64 + lane];
        bool nz = (f != 0.0f);
        unsigned long long m = __ballot(nz);
        int pre = __popcll(m & ((1ull << lane) - 1ull));
        int pos = base + pre;
        if (nz && pos < PAD)
            raw[(size_t)row * PAD + pos] = make_float2(f, __int_as_float(c * 64 + lane));
        base += __popcll(m);
    }
    if (lane == 0) nnz[row] = (base < PAD) ? base : PAD;
}

// ---- Pack raw ELL into bf16 pairs, padded to mult-of-4 pairs. ----
__global__ void pack_pairs_kernel(const float2* __restrict__ raw,
                                  const int* __restrict__ nnz,
                                  uint2* __restrict__ pairs,
                                  int* __restrict__ npairs) {
    int row = blockIdx.x;
    int i   = threadIdx.x;            // pair slot 0..127
    int cnt = nnz[row];
    int npr = ((cnt + 7) / 8) * 4;    // pairs, multiple of 4 (nnz mult of 8)
    if (i == 0) npairs[row] = npr;

    float v0 = 0.f, v1 = 0.f; int i0 = 0, i1 = 0;
    if (2 * i < cnt)     { float2 e = raw[(size_t)row * PAD + 2 * i];     v0 = e.x; i0 = __float_as_int(e.y); }
    if (2 * i + 1 < cnt) { float2 e = raw[(size_t)row * PAD + 2 * i + 1]; v1 = e.x; i1 = __float_as_int(e.y); }
    // bf16 RNE pack
    unsigned b0 = __float_as_uint(v0); b0 = (b0 + 0x7FFFu + ((b0 >> 16) & 1u)) >> 16;
    unsigned b1 = __float_as_uint(v1); b1 = (b1 + 0x7FFFu + ((b1 >> 16) & 1u)) >> 16;
    uint2 pe;
    pe.x = (b1 << 16) | b0;                       // (j1:j0) bf16x2
    pe.y = ((unsigned)i1 << 16) | (unsigned)i0;   // (idx1:idx0)
    pairs[(size_t)row * NPAIR + i] = pe;
}

// ---- Init: x = 0, rates = bf16(0.5) = 0x3F00, out = 0. Grid covers NN*PP. ----
__global__ void init_kernel(float* __restrict__ x, unsigned short* __restrict__ r,
                            float* __restrict__ out, int nout) {
    int i = blockIdx.x * blockDim.x + threadIdx.x;
    x[i] = 0.0f;
    r[i] = 0x3F00;                    // bf16 0.5 (exact)
    if (i < nout) out[i] = 0.0f;
}

// ---- One time step. Block = one row; 4 waves own blocked quarters of the
// pair list; lane owns cols 4l..4l+3. Inner: 2 nnz per iter via dot2. ----
__global__ __launch_bounds__(256) void step_kernel(
    const uint2* __restrict__ pairs, const int* __restrict__ npairs,
    const unsigned short* __restrict__ rates_in,
    unsigned short* __restrict__ rates_out,
    float* __restrict__ x, const float* __restrict__ patterns,
    const float* __restrict__ w_out, float* __restrict__ out,
    int t, int T, int with_input) {
    int row = blockIdx.x, tid = threadIdx.x;
    int w = tid >> 6, lane = tid & 63;

    __shared__ uint2 s_pr[NPAIR];
    __shared__ float s_part[4][PP];

    if (tid < NPAIR) s_pr[tid] = pairs[(size_t)row * NPAIR + tid];
    __syncthreads();

    int npr = npairs[row];            // multiple of 4
    int q   = npr >> 2;               // pairs per wave
    int s0  = w * q;

    const char* rbase = (const char*)rates_in + lane * 8;  // cols 4l..4l+3
    float4 acc = make_float4(0.f, 0.f, 0.f, 0.f);

    #pragma unroll 2
    for (int i = s0; i < s0 + q; ++i) {
        uint2 e  = s_pr[i];                           // uniform-addr broadcast
        unsigned jp = e.x;                            // (j1:j0) bf16 pair
        unsigned o0 = (e.y & 0xFFFFu) << 9;           // idx0 * 512B
        unsigned o1 = (e.y >> 16) << 9;               // idx1 * 512B
        uint2 q0 = *(const uint2*)(rbase + o0);       // row k0: cols 4l..4l+3
        uint2 q1 = *(const uint2*)(rbase + o1);       // row k1
        // repack per-column k-pairs: (k1[c] : k0[c]) bf16x2
        unsigned a0 = __builtin_amdgcn_perm(q1.x, q0.x, 0x05040100u); // col 4l
        unsigned a1 = __builtin_amdgcn_perm(q1.x, q0.x, 0x07060302u); // col 4l+1
        unsigned a2 = __builtin_amdgcn_perm(q1.y, q0.y, 0x05040100u); // col 4l+2
        unsigned a3 = __builtin_amdgcn_perm(q1.y, q0.y, 0x07060302u); // col 4l+3
        asm("v_dot2_f32_bf16 %0, %1, %2, %0" : "+v"(acc.x) : "v"(a0), "v"(jp));
        asm("v_dot2_f32_bf16 %0, %1, %2, %0" : "+v"(acc.y) : "v"(a1), "v"(jp));
        asm("v_dot2_f32_bf16 %0, %1, %2, %0" : "+v"(acc.z) : "v"(a2), "v"(jp));
        asm("v_dot2_f32_bf16 %0, %1, %2, %0" : "+v"(acc.w) : "v"(a3), "v"(jp));
    }
    ((float4*)s_part[w])[lane] = acc;                 // contiguous b128
    __syncthreads();

    float sum = s_part[0][tid] + s_part[1][tid] + s_part[2][tid] + s_part[3][tid];

    size_t off = (size_t)row * PP + tid;
    float xv  = x[off];
    float inp = with_input ? patterns[off] : 0.0f;
    xv += DT_C * (sum + inp - xv);
    x[off] = xv;
    float r = 0.5f * (1.0f + tanhf(xv));

    unsigned b  = __float_as_uint(r);                 // bf16 RNE pack
    unsigned rn = b + 0x7FFFu + ((b >> 16) & 1u);
    rates_out[off] = (unsigned short)(rn >> 16);

    if (w_out[row] != 0.0f)
        atomicAdd(&out[(size_t)tid * T + t], r * (1.0f / (float)NN));
}

extern "C" void kernel_launch(void* const* d_in, const int* in_sizes, int n_in,
                              void* d_out, int out_size, void* d_ws, size_t ws_size,
                              hipStream_t stream) {
    const float* patterns = (const float*)d_in[0];   // [N, P]
    const float* J        = (const float*)d_in[1];   // [N, N]
    const float* w_out    = (const float*)d_in[2];   // [N]
    float* out            = (float*)d_out;           // [P, T]

    int T = out_size / PP;                           // 200

    size_t off = 0;
    auto alloc = [&](size_t bytes) {
        void* p = (char*)d_ws + off;
        off += (bytes + 255) & ~(size_t)255;
        return p;
    };
    float2*         raw = (float2*)        alloc((size_t)NN * PAD * 8);
    int*            nnz = (int*)           alloc((size_t)NN * 4);
    uint2*          prs = (uint2*)         alloc((size_t)NN * NPAIR * 8);
    int*            npr = (int*)           alloc((size_t)NN * 4);
    float*          x   = (float*)         alloc((size_t)NN * PP * 4);
    unsigned short* r0  = (unsigned short*)alloc((size_t)NN * PP * 2);
    unsigned short* r1  = (unsigned short*)alloc((size_t)NN * PP * 2);
    (void)ws_size; (void)n_in; (void)in_sizes;

    build_ell_kernel<<<NN / 4, 256, 0, stream>>>(J, raw, nnz);
    pack_pairs_kernel<<<NN, NPAIR, 0, stream>>>(raw, nnz, prs, npr);
    init_kernel<<<(NN * PP) / 256, 256, 0, stream>>>(x, r0, out, PP * T);

    for (int t = 0; t < T; ++t) {
        const unsigned short* rin = (t & 1) ? r1 : r0;
        unsigned short*      rout = (t & 1) ? r0 : r1;
        step_kernel<<<NN, PP, 0, stream>>>(prs, npr, rin, rout, x, patterns,
                                           w_out, out, t, T,
                                           (t < ON_TIME_C) ? 1 : 0);
    }
}

// Round 9
// 2119.512 us; speedup vs baseline: 1.1130x; 1.1130x over previous
//
#include <hip/hip_runtime.h>
#include <hip/hip_bf16.h>

// SRNN: x_{t+1} = x + DT*(-x + J@rates + inp), rates = 0.5*(1+tanh(x)),
// out[p,t] = (w_out @ rates_t)[p] / N.
//
// v9: DENSE bf16 MFMA GEMM per step. At 5% density the sparse gather is
// mixed-bound at ~10.5us/step (v2..v8 plateau 2114-2360us); dense is
// 2.15 GFLOP/step on matrix cores (~1us) + 96 MB/step STREAMED L2 panels.
//  - J pre-converted to bf16 [2048][2048] with per-32-k permutation baked in
//    (frag k-order [0-3,16-19 | 4-7,20-23 | ...]) so each MFMA fragment is
//    one contiguous 16B chunk -> single ds_read_b128 per frag-half.
//  - rates stored TRANSPOSED [P][N] bf16, same k-permutation, written via
//    LDS-transpose in the fused epilogue.
//  - 256 blocks (1/CU), 256 thr (4 waves), BM=64 BN=32 BK=64, 32 K-steps,
//    4-buffer LDS, 3-deep global_load_lds pipeline w/ counted vmcnt
//    (issue t+2 -> vmcnt(6) -> s_barrier -> sched_barrier -> reads -> MFMA).
//  - XOR chunk swizzle (chunk ^ row&7): 2-way bank aliasing (free, m136).
//  - XCD-contiguous block swizzle: each XCD owns 4 m-panels (1MB J slice
//    stays resident in its 4MB L2 across steps).
// [history: v2 2353 sparse k-split; v7 bf16 rates 2114; v8 dot2 asm 2359;
//  coop grid.sync 25ms; 8w/CU barrier-free 2824; LDS-tile 4436.]

#define NN 2048
#define PP 256
#define DT_C 0.1f
#define ON_TIME_C 10

typedef __attribute__((ext_vector_type(8))) short bf16x8;
typedef __attribute__((ext_vector_type(4))) float f32x4;

__device__ __forceinline__ unsigned short bf16rne(float f) {
    unsigned b = __float_as_uint(f);
    return (unsigned short)((b + 0x7FFFu + ((b >> 16) & 1u)) >> 16);
}
// permutation within a 32-col group: source col s -> dest position
__device__ __forceinline__ int kperm(int s) {
    return ((s & 15) >> 2) * 8 + (s & 3) + ((s >> 4) << 2);
}

// ---- J f32 [N][N] -> J_perm bf16 [N][N], k-permuted per 32-group ----
__global__ void convert_J_kernel(const float* __restrict__ J,
                                 unsigned short* __restrict__ Jp) {
    int i = blockIdx.x * blockDim.x + threadIdx.x;   // grid covers NN*NN
    int row = i >> 11, k = i & 2047;
    Jp[((size_t)row << 11) + (k & ~31) + kperm(k & 31)] = bf16rne(J[i]);
}

// ---- x = 0, rates_T = bf16(0.5) (perm-invariant), out = 0 ----
__global__ void init_kernel(float* __restrict__ x,
                            unsigned short* __restrict__ rT,
                            float* __restrict__ out, int nout) {
    int i = blockIdx.x * blockDim.x + threadIdx.x;   // grid covers NN*PP
    x[i] = 0.0f;
    rT[i] = 0x3F00;
    if (i < nout) out[i] = 0.0f;
}

#define AS1 __attribute__((address_space(1)))
#define AS3 __attribute__((address_space(3)))
#define GLOAD16(g, l) \
    __builtin_amdgcn_global_load_lds((const AS1 void*)(g), (AS3 void*)(l), 16, 0, 0)

// ---- One time step: C = J_perm @ rates (dense MFMA) + fused epilogue ----
__global__ __launch_bounds__(256, 1) void gemm_step_kernel(
    const unsigned short* __restrict__ Jp,    // [N][N] bf16 k-permuted
    const unsigned short* __restrict__ rin,   // rates_T [P][N] bf16 k-permuted
    unsigned short* __restrict__ rout,        // rates_T [P][N]
    float* __restrict__ x, const float* __restrict__ patterns,
    const float* __restrict__ w_out, float* __restrict__ out,
    int t, int T, int with_input) {

    __shared__ char smem[49152];              // 4 bufs x (A 8KB + B 4KB)

    const int tid  = threadIdx.x;
    const int w    = tid >> 6;                // wave 0..3
    const int lane = tid & 63;
    const int wm   = w >> 1, wn = w & 1;      // wave -> (m32, n16) sub-tile

    // XCD-contiguous swizzle: XCD x = blockIdx%8 gets logical blocks
    // [32x,32x+32) = contiguous mb range -> its 1MB J slice stays L2-hot.
    const int bid   = (blockIdx.x & 7) * 32 + (blockIdx.x >> 3);
    const int mbase = (bid >> 3) * 64;
    const int nbase = (bid & 7) * 32;

    // ---- staging addresses (per lane; dest linear, source pre-swizzled) ----
    const int r8 = lane >> 3, p8 = lane & 7;
    const int xr16 = (p8 ^ r8) * 16;          // slot p holds global chunk p^r&7
    const char* gA0 = (const char*)Jp  + (((size_t)(mbase + (2*w+0)*8 + r8)) << 12) + xr16;
    const char* gA1 = (const char*)Jp  + (((size_t)(mbase + (2*w+1)*8 + r8)) << 12) + xr16;
    const char* gB  = (const char*)rin + (((size_t)(nbase +  w*8      + r8)) << 12) + xr16;
    const int ldsA0 = (2*w+0) * 1024, ldsA1 = (2*w+1) * 1024, ldsB = 8192 + w * 1024;

    // ---- fragment read offsets (within a buffer) ----
    // row r: byte r*128 + ((chunk ^ (r&7))*16); chunk = 4h + (lane>>4).
    const int cx  = ((lane >> 4) ^ (lane & 7)) * 16;
    const int vA0 = (wm*32      + (lane & 15)) * 128 + cx;
    const int vA1 = (wm*32 + 16 + (lane & 15)) * 128 + cx;
    const int vB  = 8192 + (wn*16 + (lane & 15)) * 128 + cx;   // h=1: ^64

    // ---- epilogue operand prefetch (retires under first vmcnt wait) ----
    float xv[2][4], pat[2][4], wsc[2][4];
    #pragma unroll
    for (int mf = 0; mf < 2; ++mf)
        #pragma unroll
        for (int rg = 0; rg < 4; ++rg) {
            int m = mbase + wm*32 + mf*16 + 4*(lane>>4) + rg;
            int n = nbase + wn*16 + (lane & 15);
            size_t o = ((size_t)m << 8) + n;
            xv[mf][rg]  = x[o];
            pat[mf][rg] = with_input ? patterns[o] : 0.0f;
            wsc[mf][rg] = (w_out[m] != 0.0f) ? (1.0f / (float)NN) : 0.0f;
        }

    f32x4 acc[2] = {{0.f,0.f,0.f,0.f}, {0.f,0.f,0.f,0.f}};

    // ---- prologue: stage K-steps 0 and 1 ----
    GLOAD16(gA0,       smem + 0*12288 + ldsA0);
    GLOAD16(gA1,       smem + 0*12288 + ldsA1);
    GLOAD16(gB,        smem + 0*12288 + ldsB);
    GLOAD16(gA0 + 128, smem + 1*12288 + ldsA0);
    GLOAD16(gA1 + 128, smem + 1*12288 + ldsA1);
    GLOAD16(gB  + 128, smem + 1*12288 + ldsB);

    // ---- K-loop: 32 steps of BK=64 ----
    #pragma unroll
    for (int ks = 0; ks < 32; ++ks) {
        if (ks < 30) {                        // issue stage(ks+2)
            const int bo = ((ks + 2) & 3) * 12288;
            GLOAD16(gA0 + (ks+2)*128, smem + bo + ldsA0);
            GLOAD16(gA1 + (ks+2)*128, smem + bo + ldsA1);
            GLOAD16(gB  + (ks+2)*128, smem + bo + ldsB);
        }
        // counted wait: require stage(ks) retired (leave up to 2 stages in flight)
        if (ks < 30)       asm volatile("s_waitcnt vmcnt(6)" ::: "memory");
        else if (ks == 30) asm volatile("s_waitcnt vmcnt(3)" ::: "memory");
        else               asm volatile("s_waitcnt vmcnt(0)" ::: "memory");
        __builtin_amdgcn_s_barrier();         // all waves' stage(ks) visible
        __builtin_amdgcn_sched_barrier(0);    // don't hoist reads above barrier

        const int bb = (ks & 3) * 12288;
        bf16x8 a0  = *(const bf16x8*)(smem + bb + vA0);
        bf16x8 a1  = *(const bf16x8*)(smem + bb + vA1);
        bf16x8 b0  = *(const bf16x8*)(smem + bb + vB);
        bf16x8 a0h = *(const bf16x8*)(smem + bb + (vA0 ^ 64));
        bf16x8 a1h = *(const bf16x8*)(smem + bb + (vA1 ^ 64));
        bf16x8 b0h = *(const bf16x8*)(smem + bb + (vB  ^ 64));
        acc[0] = __builtin_amdgcn_mfma_f32_16x16x32_bf16(a0,  b0,  acc[0], 0, 0, 0);
        acc[1] = __builtin_amdgcn_mfma_f32_16x16x32_bf16(a1,  b0,  acc[1], 0, 0, 0);
        acc[0] = __builtin_amdgcn_mfma_f32_16x16x32_bf16(a0h, b0h, acc[0], 0, 0, 0);
        acc[1] = __builtin_amdgcn_mfma_f32_16x16x32_bf16(a1h, b0h, acc[1], 0, 0, 0);
    }

    __syncthreads();                          // buffers dead; reuse as s_out

    // ---- epilogue: x update, tanh, readout, rates_T via LDS transpose ----
    #pragma unroll
    for (int mf = 0; mf < 2; ++mf)
        #pragma unroll
        for (int rg = 0; rg < 4; ++rg) {
            float xo = xv[mf][rg];
            float xn = xo + DT_C * (acc[mf][rg] + pat[mf][rg] - xo);
            int m = mbase + wm*32 + mf*16 + 4*(lane>>4) + rg;
            int n = nbase + wn*16 + (lane & 15);
            x[((size_t)m << 8) + n] = xn;
            float r = 0.5f * (1.0f + tanhf(xn));
            if (wsc[mf][rg] != 0.0f)
                atomicAdd(&out[(size_t)n * T + t], r * wsc[mf][rg]);
            // s_out[n_local][m-permuted], XOR-swizzled chunks
            int mloc = wm*32 + mf*16 + 4*(lane>>4) + rg;
            int pos  = (mloc & 32) + kperm(mloc & 31);
            int nloc = wn*16 + (lane & 15);
            int byte = nloc*128 + (((pos >> 3) ^ (nloc & 7)) * 16) + (pos & 7)*2;
            *(unsigned short*)(smem + byte) = bf16rne(r);
        }
    __syncthreads();
    {   // linear write-out of the block's [32 n][64 m] rates_T slab
        int nl = tid >> 3, p = tid & 7;
        uint4 v = *(const uint4*)(smem + nl*128 + ((p ^ (nl & 7)) * 16));
        *(uint4*)((char*)rout + (((size_t)(nbase + nl)) << 12) + mbase*2 + p*16) = v;
    }
}

extern "C" void kernel_launch(void* const* d_in, const int* in_sizes, int n_in,
                              void* d_out, int out_size, void* d_ws, size_t ws_size,
                              hipStream_t stream) {
    const float* patterns = (const float*)d_in[0];   // [N, P]
    const float* J        = (const float*)d_in[1];   // [N, N]
    const float* w_out    = (const float*)d_in[2];   // [N]
    float* out            = (float*)d_out;           // [P, T]

    int T = out_size / PP;                           // 200

    size_t off = 0;
    auto alloc = [&](size_t bytes) {
        void* p = (char*)d_ws + off;
        off += (bytes + 255) & ~(size_t)255;
        return p;
    };
    unsigned short* Jp = (unsigned short*)alloc((size_t)NN * NN * 2);  // 8MB
    unsigned short* r0 = (unsigned short*)alloc((size_t)PP * NN * 2);  // 1MB
    unsigned short* r1 = (unsigned short*)alloc((size_t)PP * NN * 2);  // 1MB
    float*          x  = (float*)         alloc((size_t)NN * PP * 4);  // 2MB
    (void)ws_size; (void)n_in; (void)in_sizes;

    convert_J_kernel<<<(NN * NN) / 256, 256, 0, stream>>>(J, Jp);
    init_kernel<<<(NN * PP) / 256, 256, 0, stream>>>(x, r0, out, PP * T);

    for (int t = 0; t < T; ++t) {
        const unsigned short* rin = (t & 1) ? r1 : r0;
        unsigned short*      rout = (t & 1) ? r0 : r1;
        gemm_step_kernel<<<256, 256, 0, stream>>>(Jp, rin, rout, x, patterns,
                                                  w_out, out, t, T,
                                                  (t < ON_TIME_C) ? 1 : 0);
    }
}

// Round 10
// 1972.194 us; speedup vs baseline: 1.1962x; 1.0747x over previous
//
#include <hip/hip_runtime.h>
#include <hip/hip_bf16.h>

// SRNN: x_{t+1} = x + DT*(-x + J@rates + inp), rates = 0.5*(1+tanh(x)),
// out[p,t] = (w_out @ rates_t)[p] / N.
//
// v10 = v9 dense-MFMA step with latency-hiding fixed:
//  - 512 threads (8 waves = 2/SIMD, was 4 waves = 1/SIMD: zero TLP, every
//    ds_read latency + barrier exposed -> ~2.7us/step stall at 32 phases).
//  - BK=128 per phase, 16 phases (half the barriers), 4 MFMA + 8 ds_read
//    per wave per phase, 4-buffer LDS (96KB), 2-phase-ahead global_load_lds,
//    counted vmcnt(6/3/0) at 3 loads/wave/phase.
//  - identical math order to v9 (k ascending by 32-groups) -> bit-identical
//    output (absmax must stay 1.220703e-4).
//  - J bf16 k-permuted (frag = contiguous 16B), rates_T [P][N] bf16 same
//    perm, XOR-16 chunk swizzle (~2-way banks), XCD-contiguous m-panels
//    (1MB J slice L2-resident per XCD).
// [history: sparse plateau v2 2353 / v7 2114 / v8 2359; coop sync 25ms;
//  v9 dense 4-wave 2119.]

#define NN 2048
#define PP 256
#define DT_C 0.1f
#define ON_TIME_C 10

typedef __attribute__((ext_vector_type(8))) short bf16x8;
typedef __attribute__((ext_vector_type(4))) float f32x4;

__device__ __forceinline__ unsigned short bf16rne(float f) {
    unsigned b = __float_as_uint(f);
    return (unsigned short)((b + 0x7FFFu + ((b >> 16) & 1u)) >> 16);
}
// permutation within a 32-col group: source col s -> dest position
__device__ __forceinline__ int kperm(int s) {
    return ((s & 15) >> 2) * 8 + (s & 3) + ((s >> 4) << 2);
}

// ---- J f32 [N][N] -> J_perm bf16 [N][N], k-permuted per 32-group ----
__global__ void convert_J_kernel(const float* __restrict__ J,
                                 unsigned short* __restrict__ Jp) {
    int i = blockIdx.x * blockDim.x + threadIdx.x;   // grid covers NN*NN
    int row = i >> 11, k = i & 2047;
    Jp[((size_t)row << 11) + (k & ~31) + kperm(k & 31)] = bf16rne(J[i]);
}

// ---- x = 0, rates_T = bf16(0.5) (perm-invariant), out = 0 ----
__global__ void init_kernel(float* __restrict__ x,
                            unsigned short* __restrict__ rT,
                            float* __restrict__ out, int nout) {
    int i = blockIdx.x * blockDim.x + threadIdx.x;   // grid covers NN*PP
    x[i] = 0.0f;
    rT[i] = 0x3F00;
    if (i < nout) out[i] = 0.0f;
}

#define AS1 __attribute__((address_space(1)))
#define AS3 __attribute__((address_space(3)))
#define GLOAD16(g, l) \
    __builtin_amdgcn_global_load_lds((const AS1 void*)(g), (AS3 void*)(l), 16, 0, 0)

// ---- One time step: C = J_perm @ rates (dense MFMA) + fused epilogue ----
// grid 256 (1/CU), 512 thr (8 waves). BM=64 BN=32 BK=128, 16 phases.
__global__ __launch_bounds__(512, 1) void gemm_step_kernel(
    const unsigned short* __restrict__ Jp,    // [N][N] bf16 k-permuted
    const unsigned short* __restrict__ rin,   // rates_T [P][N] bf16 k-permuted
    unsigned short* __restrict__ rout,        // rates_T [P][N]
    float* __restrict__ x, const float* __restrict__ patterns,
    const float* __restrict__ w_out, float* __restrict__ out,
    int t, int T, int with_input) {

    __shared__ char smem[98304];              // 4 bufs x (A 16KB + B 8KB)

    const int tid  = threadIdx.x;
    const int w    = tid >> 6;                // wave 0..7
    const int lane = tid & 63;
    const int wm   = w >> 1, wn = w & 1;      // wave -> (m16, n16) of 64x32

    // XCD-contiguous swizzle: XCD owns 4 contiguous m-panels (1MB J in L2).
    const int bid   = (blockIdx.x & 7) * 32 + (blockIdx.x >> 3);
    const int mbase = (bid >> 3) * 64;
    const int nbase = (bid & 7) * 32;

    // ---- staging: wave w stages A rows 8w..8w+7 (2 loads), B rows 4w..4w+3 ----
    const int rA0 = 8 * w + (lane >> 4);          // local A row, load 0
    const int rA1 = rA0 + 4;                      // load 1
    const int rB  = 4 * w + (lane >> 4);          // local B row
    const char* gA0 = (const char*)Jp  + (((size_t)(mbase + rA0)) << 12)
                      + (((lane & 15) ^ (rA0 & 15)) << 4);
    const char* gA1 = (const char*)Jp  + (((size_t)(mbase + rA1)) << 12)
                      + (((lane & 15) ^ (rA1 & 15)) << 4);
    const char* gB  = (const char*)rin + (((size_t)(nbase + rB )) << 12)
                      + (((lane & 15) ^ (rB  & 15)) << 4);
    const int ldsA0 = (8 * w)     * 256;          // uniform base (lane*16 implicit)
    const int ldsA1 = (8 * w + 4) * 256;
    const int ldsB  = 16384 + 4 * w * 256;

    // ---- fragment read rows ----
    const int mr = wm * 16 + (lane & 15);         // A row (local)
    const int nr = wn * 16 + (lane & 15);         // B row (local)

    // ---- epilogue operand prefetch (retires under first vmcnt wait) ----
    float xv[4], pat[4], wsc[4];
    #pragma unroll
    for (int rg = 0; rg < 4; ++rg) {
        int m = mbase + wm * 16 + (lane >> 4) * 4 + rg;
        int n = nbase + wn * 16 + (lane & 15);
        size_t o = ((size_t)m << 8) + n;
        xv[rg]  = x[o];
        pat[rg] = with_input ? patterns[o] : 0.0f;
        wsc[rg] = (w_out[m] != 0.0f) ? (1.0f / (float)NN) : 0.0f;
    }

    f32x4 acc = {0.f, 0.f, 0.f, 0.f};

    // ---- prologue: stage phases 0 and 1 (3 loads/wave each) ----
    GLOAD16(gA0,       smem + 0 * 24576 + ldsA0);
    GLOAD16(gA1,       smem + 0 * 24576 + ldsA1);
    GLOAD16(gB,        smem + 0 * 24576 + ldsB);
    GLOAD16(gA0 + 256, smem + 1 * 24576 + ldsA0);
    GLOAD16(gA1 + 256, smem + 1 * 24576 + ldsA1);
    GLOAD16(gB  + 256, smem + 1 * 24576 + ldsB);

    // ---- K-loop: 16 phases of BK=128 ----
    #pragma unroll
    for (int ph = 0; ph < 16; ++ph) {
        if (ph < 14) {                        // issue stage(ph+2)
            const int bo = ((ph + 2) & 3) * 24576;
            GLOAD16(gA0 + (ph + 2) * 256, smem + bo + ldsA0);
            GLOAD16(gA1 + (ph + 2) * 256, smem + bo + ldsA1);
            GLOAD16(gB  + (ph + 2) * 256, smem + bo + ldsB);
        }
        if (ph < 14)       asm volatile("s_waitcnt vmcnt(6)" ::: "memory");
        else if (ph == 14) asm volatile("s_waitcnt vmcnt(3)" ::: "memory");
        else               asm volatile("s_waitcnt vmcnt(0)" ::: "memory");
        __builtin_amdgcn_s_barrier();         // stage(ph) visible to all waves
        __builtin_amdgcn_sched_barrier(0);    // don't hoist reads above barrier

        const int bb = (ph & 3) * 24576;
        bf16x8 a[4], b[4];
        #pragma unroll
        for (int g = 0; g < 4; ++g) {
            int c = g * 4 + (lane >> 4);      // 16B chunk index in 256B row
            a[g] = *(const bf16x8*)(smem + bb + mr * 256 + ((c ^ (mr & 15)) << 4));
            b[g] = *(const bf16x8*)(smem + bb + 16384 + nr * 256 + ((c ^ (nr & 15)) << 4));
        }
        #pragma unroll
        for (int g = 0; g < 4; ++g)           // k ascending: bit-identical to v9
            acc = __builtin_amdgcn_mfma_f32_16x16x32_bf16(a[g], b[g], acc, 0, 0, 0);
    }

    __syncthreads();                          // buffers dead; reuse as s_out

    // ---- epilogue: x update, tanh, readout, rates_T via LDS transpose ----
    #pragma unroll
    for (int rg = 0; rg < 4; ++rg) {
        float xo = xv[rg];
        float xn = xo + DT_C * (acc[rg] + pat[rg] - xo);
        int mloc = wm * 16 + (lane >> 4) * 4 + rg;
        int nloc = wn * 16 + (lane & 15);
        int m = mbase + mloc, n = nbase + nloc;
        x[((size_t)m << 8) + n] = xn;
        float r = 0.5f * (1.0f + tanhf(xn));
        if (wsc[rg] != 0.0f)
            atomicAdd(&out[(size_t)n * T + t], r * wsc[rg]);
        // s_out[nloc][m-permuted], XOR-swizzled 16B chunks
        int pos  = (mloc & ~31) + kperm(mloc & 31);
        int byte = nloc * 128 + (((pos >> 3) ^ (nloc & 7)) << 4) + (pos & 7) * 2;
        *(unsigned short*)(smem + byte) = bf16rne(r);
    }
    __syncthreads();
    if (tid < 256) {   // linear write-out of the block's [32 n][64 m] slab
        int nl = tid >> 3, p = tid & 7;
        uint4 v = *(const uint4*)(smem + nl * 128 + ((p ^ (nl & 7)) << 4));
        *(uint4*)((char*)rout + (((size_t)(nbase + nl)) << 12) + mbase * 2 + p * 16) = v;
    }
}

extern "C" void kernel_launch(void* const* d_in, const int* in_sizes, int n_in,
                              void* d_out, int out_size, void* d_ws, size_t ws_size,
                              hipStream_t stream) {
    const float* patterns = (const float*)d_in[0];   // [N, P]
    const float* J        = (const float*)d_in[1];   // [N, N]
    const float* w_out    = (const float*)d_in[2];   // [N]
    float* out            = (float*)d_out;           // [P, T]

    int T = out_size / PP;                           // 200

    size_t off = 0;
    auto alloc = [&](size_t bytes) {
        void* p = (char*)d_ws + off;
        off += (bytes + 255) & ~(size_t)255;
        return p;
    };
    unsigned short* Jp = (unsigned short*)alloc((size_t)NN * NN * 2);  // 8MB
    unsigned short* r0 = (unsigned short*)alloc((size_t)PP * NN * 2);  // 1MB
    unsigned short* r1 = (unsigned short*)alloc((size_t)PP * NN * 2);  // 1MB
    float*          x  = (float*)         alloc((size_t)NN * PP * 4);  // 2MB
    (void)ws_size; (void)n_in; (void)in_sizes;

    convert_J_kernel<<<(NN * NN) / 256, 256, 0, stream>>>(J, Jp);
    init_kernel<<<(NN * PP) / 256, 256, 0, stream>>>(x, r0, out, PP * T);

    for (int t = 0; t < T; ++t) {
        const unsigned short* rin = (t & 1) ? r1 : r0;
        unsigned short*      rout = (t & 1) ? r0 : r1;
        gemm_step_kernel<<<256, 512, 0, stream>>>(Jp, rin, rout, x, patterns,
                                                  w_out, out, t, T,
                                                  (t < ON_TIME_C) ? 1 : 0);
    }
}